// Round 6
// baseline (565.044 us; speedup 1.0000x reference)
//
#include <hip/hip_runtime.h>
#include <hip/hip_bf16.h>
#include <cstdint>
#include <cstddef>

#define Bdim 2
#define Sdim 2048
#define Edim 1024
#define Hdim 16
#define Ddim 64
#define KVB 128
#define MROWS (Bdim*Sdim)

typedef __bf16 bf16_t;
typedef __attribute__((ext_vector_type(8))) __bf16 bf16x8;
typedef __attribute__((ext_vector_type(4))) __bf16 bf16x4;
typedef __attribute__((ext_vector_type(4))) float f32x4;

__device__ inline bf16_t f2b(float x) {
    unsigned u = __builtin_bit_cast(unsigned, x);
    unsigned r = u + 0x7fffu + ((u >> 16) & 1u);
    return __builtin_bit_cast(bf16_t, (unsigned short)(r >> 16));
}

// Stage a ROWS x 32 tile (row-major, leading dim ld) into LDS as bf16, rows
// padded to 40 elements. Converts f32 -> bf16 on the fly when T == float.
template<typename T, int ROWS>
__device__ inline void stage_tile(bf16_t* dst, const T* src, int ld, int tid) {
    for (int i = tid; i < ROWS * 4; i += 256) {
        int r = i >> 2;
        int c = (i & 3) * 8;
        const T* s = src + (size_t)r * ld + c;
        bf16x8 v;
        if constexpr (sizeof(T) == 4) {
            const float4* sf = (const float4*)s;
            float4 a = sf[0], b = sf[1];
            v[0] = f2b(a.x); v[1] = f2b(a.y); v[2] = f2b(a.z); v[3] = f2b(a.w);
            v[4] = f2b(b.x); v[5] = f2b(b.y); v[6] = f2b(b.z); v[7] = f2b(b.w);
        } else {
            v = *(const bf16x8*)s;
        }
        *(bf16x8*)(dst + r * 40 + c) = v;
    }
}

// Core: C[128 x BN] += A[128 x K] * B^T, B row-major [BN x K]. 4 waves 2x2.
template<typename TA, typename TB, int FN>
__device__ inline void gemm_core(const TA* A, int lda, const TB* B, int ldb, int K,
                                 f32x4 (&acc)[4][FN]) {
    constexpr int BN = FN * 32;
    __shared__ bf16_t As[128 * 40];
    __shared__ bf16_t Bs[BN * 40];
    const int tid = threadIdx.x;
    const int lane = tid & 63;
    const int w = tid >> 6;
    const int wm = w >> 1, wn = w & 1;
    const int lr = lane & 15, lg = lane >> 4;

    #pragma unroll
    for (int mi = 0; mi < 4; ++mi)
        #pragma unroll
        for (int ni = 0; ni < FN; ++ni)
            acc[mi][ni] = (f32x4){0.f, 0.f, 0.f, 0.f};

    for (int kt = 0; kt < K; kt += 32) {
        __syncthreads();
        stage_tile<TA, 128>(As, A + kt, lda, tid);
        stage_tile<TB, BN>(Bs, B + kt, ldb, tid);
        __syncthreads();
        bf16x8 af[4], bf[FN];
        #pragma unroll
        for (int mi = 0; mi < 4; ++mi)
            af[mi] = *(const bf16x8*)&As[(wm * 64 + mi * 16 + lr) * 40 + lg * 8];
        #pragma unroll
        for (int ni = 0; ni < FN; ++ni)
            bf[ni] = *(const bf16x8*)&Bs[(wn * (FN * 16) + ni * 16 + lr) * 40 + lg * 8];
        #pragma unroll
        for (int mi = 0; mi < 4; ++mi)
            #pragma unroll
            for (int ni = 0; ni < FN; ++ni)
                acc[mi][ni] = __builtin_amdgcn_mfma_f32_16x16x32_bf16(
                    af[mi], bf[ni], acc[mi][ni], 0, 0, 0);
    }
}

// ---- Kernel 0: convert the 4 weight matrices to bf16; Wq scaled by 0.125.
__global__ __launch_bounds__(256) void k_convert(
    const float* __restrict__ Wq, const float* __restrict__ Wk,
    const float* __restrict__ Wv, const float* __restrict__ Wo,
    bf16_t* __restrict__ dst) {
    const int z = blockIdx.y;
    const float* src = (z == 0) ? Wq : (z == 1) ? Wk : (z == 2) ? Wv : Wo;
    const float scale = (z == 0) ? 0.125f : 1.0f;
    bf16_t* d = dst + (size_t)z * Edim * Edim;
    const int i = blockIdx.x * 256 + threadIdx.x;
    const float4* s4 = (const float4*)(src + (size_t)i * 8);
    float4 a = s4[0], b = s4[1];
    bf16x8 v;
    v[0] = f2b(a.x * scale); v[1] = f2b(a.y * scale);
    v[2] = f2b(a.z * scale); v[3] = f2b(a.w * scale);
    v[4] = f2b(b.x * scale); v[5] = f2b(b.y * scale);
    v[6] = f2b(b.z * scale); v[7] = f2b(b.w * scale);
    *(bf16x8*)(d + (size_t)i * 8) = v;
}

// ---- Kernel 1: QKV projections. z = 0/1/2 -> Q/K/V. W pre-converted bf16.
// Q (pre-scaled by 0.125),K -> [B,H,S,D] bf16; V -> transposed [B,H,D,S] bf16.
__global__ __launch_bounds__(256) void k_proj(
    const float* __restrict__ xq, const float* __restrict__ xk, const float* __restrict__ xv,
    const bf16_t* __restrict__ Wb,
    const float* __restrict__ bq, const float* __restrict__ bk, const float* __restrict__ bv,
    bf16_t* __restrict__ Qb, bf16_t* __restrict__ Kb, bf16_t* __restrict__ Vtb) {
    const int z = blockIdx.z;
    const float* X = (z == 0) ? xq : (z == 1) ? xk : xv;
    const bf16_t* W = Wb + (size_t)z * Edim * Edim;
    const float* bias = (z == 0) ? bq : (z == 1) ? bk : bv;
    const float bscale = (z == 0) ? 0.125f : 1.0f;
    const int tm = blockIdx.y, tn = blockIdx.x;
    f32x4 acc[4][4];
    gemm_core<float, bf16_t, 4>(X + (size_t)tm * 128 * Edim, Edim,
                                W + (size_t)tn * 128 * Edim, Edim, Edim, acc);
    const int tid = threadIdx.x, lane = tid & 63, w = tid >> 6;
    const int wm = w >> 1, wn = w & 1, lr = lane & 15, lg = lane >> 4;
    #pragma unroll
    for (int mi = 0; mi < 4; ++mi)
        #pragma unroll
        for (int ni = 0; ni < 4; ++ni)
            #pragma unroll
            for (int j = 0; j < 4; ++j) {
                int gm = tm * 128 + wm * 64 + mi * 16 + lg * 4 + j;
                int gn = tn * 128 + wn * 64 + ni * 16 + lr;
                float v = acc[mi][ni][j] + bias[gn] * bscale;
                int b = gm >> 11, s = gm & (Sdim - 1);
                int h = gn >> 6, d = gn & (Ddim - 1);
                if (z == 2)
                    Vtb[((size_t)(b * Hdim + h) * Ddim + d) * Sdim + s] = f2b(v);
                else if (z == 0)
                    Qb[((size_t)(b * Hdim + h) * Sdim + s) * Ddim + d] = f2b(v);
                else
                    Kb[((size_t)(b * Hdim + h) * Sdim + s) * Ddim + d] = f2b(v);
            }
}

// ---- Kernel 2: fused attention v4 = v3 with PLAIN (cached) P stores.
// A/B vs round 5: only the nontemporal hint removed — NT stores bypass L2 and
// stall the wave on HBM write completion each tile (vmcnt shared with loads);
// plain stores let L2 absorb and drain asynchronously.
__global__ __launch_bounds__(256) void k_attn(
    const bf16_t* __restrict__ Qb, const bf16_t* __restrict__ Kb,
    const bf16_t* __restrict__ Vtb, float* __restrict__ P, bf16_t* __restrict__ AOb) {
    const int bh = blockIdx.y, b = bh >> 4, h = bh & 15;
    const int qt = blockIdx.x;
    const int tid = threadIdx.x, lane = tid & 63, w = tid >> 6;
    const int lr = lane & 15, lg = lane >> 4;

    __shared__ bf16_t Ps[4][16][132];   // per-wave 16x128 P band (bf16)

    const bf16_t* Qp = Qb + ((size_t)bh * Sdim + qt * 64 + w * 16) * Ddim;
    const bf16_t* Kp = Kb + (size_t)bh * Sdim * Ddim;
    const bf16_t* Vp = Vtb + (size_t)bh * Ddim * Sdim;
    float* Pp = P + (size_t)bh * Sdim * Sdim + (size_t)(qt * 64 + w * 16) * Sdim;

    // Q fragments for this wave's 16 q-rows (pre-scaled by 1/8 at projection).
    bf16x8 qf[2];
    #pragma unroll
    for (int kk = 0; kk < 2; ++kk)
        qf[kk] = *(const bf16x8*)(Qp + lr * Ddim + kk * 32 + lg * 8);

    // ---------------- Phase 1: row sums of exp(s) (no barriers, no shfl in loop)
    float lsum[4] = {0.f, 0.f, 0.f, 0.f};
    for (int kt = 0; kt < Sdim / KVB; ++kt) {
        f32x4 sacc[8];
        #pragma unroll
        for (int ni = 0; ni < 8; ++ni) sacc[ni] = (f32x4){0.f, 0.f, 0.f, 0.f};
        #pragma unroll
        for (int ni = 0; ni < 8; ++ni) {
            const bf16_t* kp = Kp + (size_t)(kt * KVB + ni * 16 + lr) * Ddim;
            bf16x8 kf0 = *(const bf16x8*)(kp + lg * 8);
            bf16x8 kf1 = *(const bf16x8*)(kp + 32 + lg * 8);
            sacc[ni] = __builtin_amdgcn_mfma_f32_16x16x32_bf16(qf[0], kf0, sacc[ni], 0, 0, 0);
            sacc[ni] = __builtin_amdgcn_mfma_f32_16x16x32_bf16(qf[1], kf1, sacc[ni], 0, 0, 0);
        }
        #pragma unroll
        for (int ni = 0; ni < 8; ++ni)
            #pragma unroll
            for (int j = 0; j < 4; ++j)
                lsum[j] += __expf(sacc[ni][j]);
    }
    #pragma unroll
    for (int mask = 1; mask <= 8; mask <<= 1)
        #pragma unroll
        for (int j = 0; j < 4; ++j)
            lsum[j] += __shfl_xor(lsum[j], mask);
    float il[4];
    #pragma unroll
    for (int j = 0; j < 4; ++j) il[j] = 1.0f / lsum[j];

    // ---------------- Phase 2: P write + O = P.V (no barriers) ----------------
    f32x4 oacc[4];
    #pragma unroll
    for (int nd = 0; nd < 4; ++nd) oacc[nd] = (f32x4){0.f, 0.f, 0.f, 0.f};

    for (int kt = 0; kt < Sdim / KVB; ++kt) {
        #pragma unroll
        for (int ni = 0; ni < 8; ++ni) {
            const bf16_t* kp = Kp + (size_t)(kt * KVB + ni * 16 + lr) * Ddim;
            bf16x8 kf0 = *(const bf16x8*)(kp + lg * 8);
            bf16x8 kf1 = *(const bf16x8*)(kp + 32 + lg * 8);
            f32x4 s = (f32x4){0.f, 0.f, 0.f, 0.f};
            s = __builtin_amdgcn_mfma_f32_16x16x32_bf16(qf[0], kf0, s, 0, 0, 0);
            s = __builtin_amdgcn_mfma_f32_16x16x32_bf16(qf[1], kf1, s, 0, 0, 0);
            #pragma unroll
            for (int j = 0; j < 4; ++j)
                Ps[w][lg * 4 + j][ni * 16 + lr] = f2b(__expf(s[j]) * il[j]);
        }
        // coalesced global P write from LDS band: f32x4 per lane, 2 rows/instr
        #pragma unroll
        for (int i = 0; i < 8; ++i) {
            int row = 2 * i + (lane >> 5);
            int col0 = (lane & 31) * 4;
            bf16x4 p4 = *(const bf16x4*)&Ps[w][row][col0];
            f32x4 o;
            o[0] = (float)p4[0]; o[1] = (float)p4[1];
            o[2] = (float)p4[2]; o[3] = (float)p4[3];
            *(f32x4*)&Pp[(size_t)row * Sdim + kt * KVB + col0] = o;
        }
        // PV accumulate from LDS band
        #pragma unroll
        for (int ks = 0; ks < 4; ++ks) {
            bf16x8 pa = *(const bf16x8*)&Ps[w][lr][ks * 32 + lg * 8];
            #pragma unroll
            for (int nd = 0; nd < 4; ++nd) {
                bf16x8 vf = *(const bf16x8*)(Vp + (size_t)(nd * 16 + lr) * Sdim + kt * KVB + ks * 32 + lg * 8);
                oacc[nd] = __builtin_amdgcn_mfma_f32_16x16x32_bf16(pa, vf, oacc[nd], 0, 0, 0);
            }
        }
    }

    // epilogue: AO bf16 [B,S,E]
    #pragma unroll
    for (int nd = 0; nd < 4; ++nd)
        #pragma unroll
        for (int j = 0; j < 4; ++j) {
            int s = qt * 64 + w * 16 + lg * 4 + j;
            int d = nd * 16 + lr;
            AOb[((size_t)(b * Sdim + s)) * Edim + h * Ddim + d] = f2b(oacc[nd][j]);
        }
}

// ---- Kernel 3: output = AO @ Wo^T + bo -> d_out f32. Wo pre-converted bf16.
__global__ __launch_bounds__(256) void k_oproj(
    const bf16_t* __restrict__ AOb, const bf16_t* __restrict__ Wob,
    const float* __restrict__ bo, float* __restrict__ out) {
    f32x4 acc[4][4];
    gemm_core<bf16_t, bf16_t, 4>(AOb + (size_t)blockIdx.y * 128 * Edim, Edim,
                                 Wob + (size_t)blockIdx.x * 128 * Edim, Edim, Edim, acc);
    const int tid = threadIdx.x, lane = tid & 63, w = tid >> 6;
    const int wm = w >> 1, wn = w & 1, lr = lane & 15, lg = lane >> 4;
    #pragma unroll
    for (int mi = 0; mi < 4; ++mi)
        #pragma unroll
        for (int ni = 0; ni < 4; ++ni)
            #pragma unroll
            for (int j = 0; j < 4; ++j) {
                int gm = blockIdx.y * 128 + wm * 64 + mi * 16 + lg * 4 + j;
                int gn = blockIdx.x * 128 + wn * 64 + ni * 16 + lr;
                out[(size_t)gm * Edim + gn] = acc[mi][ni][j] + bo[gn];
            }
}

extern "C" void kernel_launch(void* const* d_in, const int* in_sizes, int n_in,
                              void* d_out, int out_size, void* d_ws, size_t ws_size,
                              hipStream_t stream) {
    const float* query = (const float*)d_in[0];
    const float* key_  = (const float*)d_in[1];
    const float* value = (const float*)d_in[2];
    const float* Wq = (const float*)d_in[3];
    const float* bq = (const float*)d_in[4];
    const float* Wk = (const float*)d_in[5];
    const float* bk = (const float*)d_in[6];
    const float* Wv = (const float*)d_in[7];
    const float* bv = (const float*)d_in[8];
    const float* Wo = (const float*)d_in[9];
    const float* bo = (const float*)d_in[10];

    float* out = (float*)d_out;                      // [4096][1024]
    float* P = out + (size_t)MROWS * Edim;           // [32][2048][2048] attn weights

    const size_t WSZ = (size_t)Edim * Edim;                 // 1M elems per W
    const size_t HSD = (size_t)Bdim * Hdim * Sdim * Ddim;   // 4M elems
    bf16_t* Wb  = (bf16_t*)d_ws;        // 4 x [E,E]  (Wq*0.125, Wk, Wv, Wo)
    bf16_t* Qb  = Wb + 4 * WSZ;         // [B,H,S,D]  (pre-scaled)
    bf16_t* Kb  = Qb + HSD;             // [B,H,S,D]
    bf16_t* Vtb = Kb + HSD;             // [B,H,D,S]
    bf16_t* AOb = Vtb + HSD;            // [B,S,E]

    k_convert<<<dim3(512, 4), 256, 0, stream>>>(Wq, Wk, Wv, Wo, Wb);
    k_proj<<<dim3(8, 32, 3), 256, 0, stream>>>(query, key_, value, Wb,
                                               bq, bk, bv, Qb, Kb, Vtb);
    k_attn<<<dim3(32, 32), 256, 0, stream>>>(Qb, Kb, Vtb, P, AOb);
    k_oproj<<<dim3(8, 32, 1), 256, 0, stream>>>(AOb, Wb + 3 * WSZ, bo, out);
}

// Round 7
// 535.019 us; speedup vs baseline: 1.0561x; 1.0561x over previous
//
#include <hip/hip_runtime.h>
#include <hip/hip_bf16.h>
#include <cstdint>
#include <cstddef>

#define Bdim 2
#define Sdim 2048
#define Edim 1024
#define Hdim 16
#define Ddim 64
#define KVB 128
#define MROWS (Bdim*Sdim)

typedef __bf16 bf16_t;
typedef __attribute__((ext_vector_type(8))) __bf16 bf16x8;
typedef __attribute__((ext_vector_type(4))) __bf16 bf16x4;
typedef __attribute__((ext_vector_type(4))) float f32x4;

__device__ inline bf16_t f2b(float x) {
    unsigned u = __builtin_bit_cast(unsigned, x);
    unsigned r = u + 0x7fffu + ((u >> 16) & 1u);
    return __builtin_bit_cast(bf16_t, (unsigned short)(r >> 16));
}

// Stage a ROWS x 32 tile (row-major, leading dim ld) into LDS as bf16, rows
// padded to 40 elements. Converts f32 -> bf16 on the fly when T == float.
template<typename T, int ROWS>
__device__ inline void stage_tile(bf16_t* dst, const T* src, int ld, int tid) {
    for (int i = tid; i < ROWS * 4; i += 256) {
        int r = i >> 2;
        int c = (i & 3) * 8;
        const T* s = src + (size_t)r * ld + c;
        bf16x8 v;
        if constexpr (sizeof(T) == 4) {
            const float4* sf = (const float4*)s;
            float4 a = sf[0], b = sf[1];
            v[0] = f2b(a.x); v[1] = f2b(a.y); v[2] = f2b(a.z); v[3] = f2b(a.w);
            v[4] = f2b(b.x); v[5] = f2b(b.y); v[6] = f2b(b.z); v[7] = f2b(b.w);
        } else {
            v = *(const bf16x8*)s;
        }
        *(bf16x8*)(dst + r * 40 + c) = v;
    }
}

// Core: C[128 x BN] += A[128 x K] * B^T, B row-major [BN x K]. 4 waves 2x2.
template<typename TA, typename TB, int FN>
__device__ inline void gemm_core(const TA* A, int lda, const TB* B, int ldb, int K,
                                 f32x4 (&acc)[4][FN]) {
    constexpr int BN = FN * 32;
    __shared__ bf16_t As[128 * 40];
    __shared__ bf16_t Bs[BN * 40];
    const int tid = threadIdx.x;
    const int lane = tid & 63;
    const int w = tid >> 6;
    const int wm = w >> 1, wn = w & 1;
    const int lr = lane & 15, lg = lane >> 4;

    #pragma unroll
    for (int mi = 0; mi < 4; ++mi)
        #pragma unroll
        for (int ni = 0; ni < FN; ++ni)
            acc[mi][ni] = (f32x4){0.f, 0.f, 0.f, 0.f};

    for (int kt = 0; kt < K; kt += 32) {
        __syncthreads();
        stage_tile<TA, 128>(As, A + kt, lda, tid);
        stage_tile<TB, BN>(Bs, B + kt, ldb, tid);
        __syncthreads();
        bf16x8 af[4], bf[FN];
        #pragma unroll
        for (int mi = 0; mi < 4; ++mi)
            af[mi] = *(const bf16x8*)&As[(wm * 64 + mi * 16 + lr) * 40 + lg * 8];
        #pragma unroll
        for (int ni = 0; ni < FN; ++ni)
            bf[ni] = *(const bf16x8*)&Bs[(wn * (FN * 16) + ni * 16 + lr) * 40 + lg * 8];
        #pragma unroll
        for (int mi = 0; mi < 4; ++mi)
            #pragma unroll
            for (int ni = 0; ni < FN; ++ni)
                acc[mi][ni] = __builtin_amdgcn_mfma_f32_16x16x32_bf16(
                    af[mi], bf[ni], acc[mi][ni], 0, 0, 0);
    }
}

// ---- Kernel 0: convert the 4 weight matrices to bf16; Wq scaled by 0.125.
__global__ __launch_bounds__(256) void k_convert(
    const float* __restrict__ Wq, const float* __restrict__ Wk,
    const float* __restrict__ Wv, const float* __restrict__ Wo,
    bf16_t* __restrict__ dst) {
    const int z = blockIdx.y;
    const float* src = (z == 0) ? Wq : (z == 1) ? Wk : (z == 2) ? Wv : Wo;
    const float scale = (z == 0) ? 0.125f : 1.0f;
    bf16_t* d = dst + (size_t)z * Edim * Edim;
    const int i = blockIdx.x * 256 + threadIdx.x;
    const float4* s4 = (const float4*)(src + (size_t)i * 8);
    float4 a = s4[0], b = s4[1];
    bf16x8 v;
    v[0] = f2b(a.x * scale); v[1] = f2b(a.y * scale);
    v[2] = f2b(a.z * scale); v[3] = f2b(a.w * scale);
    v[4] = f2b(b.x * scale); v[5] = f2b(b.y * scale);
    v[6] = f2b(b.z * scale); v[7] = f2b(b.w * scale);
    *(bf16x8*)(d + (size_t)i * 8) = v;
}

// ---- Kernel 1: QKV projections. z = 0/1/2 -> Q/K/V. W pre-converted bf16.
// Q (pre-scaled by 0.125),K -> [B,H,S,D] bf16; V -> transposed [B,H,D,S] bf16.
__global__ __launch_bounds__(256) void k_proj(
    const float* __restrict__ xq, const float* __restrict__ xk, const float* __restrict__ xv,
    const bf16_t* __restrict__ Wb,
    const float* __restrict__ bq, const float* __restrict__ bk, const float* __restrict__ bv,
    bf16_t* __restrict__ Qb, bf16_t* __restrict__ Kb, bf16_t* __restrict__ Vtb) {
    const int z = blockIdx.z;
    const float* X = (z == 0) ? xq : (z == 1) ? xk : xv;
    const bf16_t* W = Wb + (size_t)z * Edim * Edim;
    const float* bias = (z == 0) ? bq : (z == 1) ? bk : bv;
    const float bscale = (z == 0) ? 0.125f : 1.0f;
    const int tm = blockIdx.y, tn = blockIdx.x;
    f32x4 acc[4][4];
    gemm_core<float, bf16_t, 4>(X + (size_t)tm * 128 * Edim, Edim,
                                W + (size_t)tn * 128 * Edim, Edim, Edim, acc);
    const int tid = threadIdx.x, lane = tid & 63, w = tid >> 6;
    const int wm = w >> 1, wn = w & 1, lr = lane & 15, lg = lane >> 4;
    #pragma unroll
    for (int mi = 0; mi < 4; ++mi)
        #pragma unroll
        for (int ni = 0; ni < 4; ++ni)
            #pragma unroll
            for (int j = 0; j < 4; ++j) {
                int gm = tm * 128 + wm * 64 + mi * 16 + lg * 4 + j;
                int gn = tn * 128 + wn * 64 + ni * 16 + lr;
                float v = acc[mi][ni][j] + bias[gn] * bscale;
                int b = gm >> 11, s = gm & (Sdim - 1);
                int h = gn >> 6, d = gn & (Ddim - 1);
                if (z == 2)
                    Vtb[((size_t)(b * Hdim + h) * Ddim + d) * Sdim + s] = f2b(v);
                else if (z == 0)
                    Qb[((size_t)(b * Hdim + h) * Sdim + s) * Ddim + d] = f2b(v);
                else
                    Kb[((size_t)(b * Hdim + h) * Sdim + s) * Ddim + d] = f2b(v);
            }
}

// ---- Kernel 2: fused attention v5 = v4 + XCD swizzle + batched loads.
// (a) XCD-aware block mapping: XCD k handles bh in [4k,4k+4) only, so each
//     XCD's K/V working set is 2 MB < 4 MB L2 (was ~16 MB -> L3 latency).
// (b) K/V fragment loads batched into arrays before the MFMA blocks: ~16
//     loads in flight per wave instead of ~5 (VGPR was 48 -> latency chains).
__global__ __launch_bounds__(256) void k_attn(
    const bf16_t* __restrict__ Qb, const bf16_t* __restrict__ Kb,
    const bf16_t* __restrict__ Vtb, float* __restrict__ P, bf16_t* __restrict__ AOb) {
    // XCD swizzle: hardware assigns block n to XCD n%8; give XCD k a
    // contiguous bh range. id = (n%8)*128 + n/8; bh = id/32, qt = id%32.
    const int wg = blockIdx.x;
    const int id = ((wg & 7) << 7) | (wg >> 3);
    const int bh = id >> 5, qt = id & 31;
    const int b = bh >> 4, h = bh & 15;
    const int tid = threadIdx.x, lane = tid & 63, w = tid >> 6;
    const int lr = lane & 15, lg = lane >> 4;

    __shared__ bf16_t Ps[4][16][132];   // per-wave 16x128 P band (bf16)

    const bf16_t* Qp = Qb + ((size_t)bh * Sdim + qt * 64 + w * 16) * Ddim;
    const bf16_t* Kp = Kb + (size_t)bh * Sdim * Ddim;
    const bf16_t* Vp = Vtb + (size_t)bh * Ddim * Sdim;
    float* Pp = P + (size_t)bh * Sdim * Sdim + (size_t)(qt * 64 + w * 16) * Sdim;

    // Q fragments for this wave's 16 q-rows (pre-scaled by 1/8 at projection).
    bf16x8 qf[2];
    #pragma unroll
    for (int kk = 0; kk < 2; ++kk)
        qf[kk] = *(const bf16x8*)(Qp + lr * Ddim + kk * 32 + lg * 8);

    // ---------------- Phase 1: row sums of exp(s) ----------------
    float lsum[4] = {0.f, 0.f, 0.f, 0.f};
    for (int kt = 0; kt < Sdim / KVB; ++kt) {
        // batch all 16 K-fragment loads first (deep load burst)
        bf16x8 kf[8][2];
        #pragma unroll
        for (int ni = 0; ni < 8; ++ni) {
            const bf16_t* kp = Kp + (size_t)(kt * KVB + ni * 16 + lr) * Ddim;
            kf[ni][0] = *(const bf16x8*)(kp + lg * 8);
            kf[ni][1] = *(const bf16x8*)(kp + 32 + lg * 8);
        }
        f32x4 sacc[8];
        #pragma unroll
        for (int ni = 0; ni < 8; ++ni) {
            sacc[ni] = (f32x4){0.f, 0.f, 0.f, 0.f};
            sacc[ni] = __builtin_amdgcn_mfma_f32_16x16x32_bf16(qf[0], kf[ni][0], sacc[ni], 0, 0, 0);
            sacc[ni] = __builtin_amdgcn_mfma_f32_16x16x32_bf16(qf[1], kf[ni][1], sacc[ni], 0, 0, 0);
        }
        #pragma unroll
        for (int ni = 0; ni < 8; ++ni)
            #pragma unroll
            for (int j = 0; j < 4; ++j)
                lsum[j] += __expf(sacc[ni][j]);
    }
    #pragma unroll
    for (int mask = 1; mask <= 8; mask <<= 1)
        #pragma unroll
        for (int j = 0; j < 4; ++j)
            lsum[j] += __shfl_xor(lsum[j], mask);
    float il[4];
    #pragma unroll
    for (int j = 0; j < 4; ++j) il[j] = 1.0f / lsum[j];

    // ---------------- Phase 2: P write + O = P.V ----------------
    f32x4 oacc[4];
    #pragma unroll
    for (int nd = 0; nd < 4; ++nd) oacc[nd] = (f32x4){0.f, 0.f, 0.f, 0.f};

    for (int kt = 0; kt < Sdim / KVB; ++kt) {
        bf16x8 kf[8][2];
        #pragma unroll
        for (int ni = 0; ni < 8; ++ni) {
            const bf16_t* kp = Kp + (size_t)(kt * KVB + ni * 16 + lr) * Ddim;
            kf[ni][0] = *(const bf16x8*)(kp + lg * 8);
            kf[ni][1] = *(const bf16x8*)(kp + 32 + lg * 8);
        }
        #pragma unroll
        for (int ni = 0; ni < 8; ++ni) {
            f32x4 s = (f32x4){0.f, 0.f, 0.f, 0.f};
            s = __builtin_amdgcn_mfma_f32_16x16x32_bf16(qf[0], kf[ni][0], s, 0, 0, 0);
            s = __builtin_amdgcn_mfma_f32_16x16x32_bf16(qf[1], kf[ni][1], s, 0, 0, 0);
            #pragma unroll
            for (int j = 0; j < 4; ++j)
                Ps[w][lg * 4 + j][ni * 16 + lr] = f2b(__expf(s[j]) * il[j]);
        }
        // batch V loads for the whole tile
        bf16x8 vf[4][4];
        #pragma unroll
        for (int ks = 0; ks < 4; ++ks)
            #pragma unroll
            for (int nd = 0; nd < 4; ++nd)
                vf[ks][nd] = *(const bf16x8*)(Vp + (size_t)(nd * 16 + lr) * Sdim + kt * KVB + ks * 32 + lg * 8);
        // coalesced global P write from LDS band: f32x4 per lane, 2 rows/instr
        #pragma unroll
        for (int i = 0; i < 8; ++i) {
            int row = 2 * i + (lane >> 5);
            int col0 = (lane & 31) * 4;
            bf16x4 p4 = *(const bf16x4*)&Ps[w][row][col0];
            f32x4 o;
            o[0] = (float)p4[0]; o[1] = (float)p4[1];
            o[2] = (float)p4[2]; o[3] = (float)p4[3];
            *(f32x4*)&Pp[(size_t)row * Sdim + kt * KVB + col0] = o;
        }
        // PV accumulate from LDS band
        #pragma unroll
        for (int ks = 0; ks < 4; ++ks) {
            bf16x8 pa = *(const bf16x8*)&Ps[w][lr][ks * 32 + lg * 8];
            #pragma unroll
            for (int nd = 0; nd < 4; ++nd)
                oacc[nd] = __builtin_amdgcn_mfma_f32_16x16x32_bf16(pa, vf[ks][nd], oacc[nd], 0, 0, 0);
        }
    }

    // epilogue: AO bf16 [B,S,E]
    #pragma unroll
    for (int nd = 0; nd < 4; ++nd)
        #pragma unroll
        for (int j = 0; j < 4; ++j) {
            int s = qt * 64 + w * 16 + lg * 4 + j;
            int d = nd * 16 + lr;
            AOb[((size_t)(b * Sdim + s)) * Edim + h * Ddim + d] = f2b(oacc[nd][j]);
        }
}

// ---- Kernel 3: output = AO @ Wo^T + bo -> d_out f32. Wo pre-converted bf16.
__global__ __launch_bounds__(256) void k_oproj(
    const bf16_t* __restrict__ AOb, const bf16_t* __restrict__ Wob,
    const float* __restrict__ bo, float* __restrict__ out) {
    f32x4 acc[4][4];
    gemm_core<bf16_t, bf16_t, 4>(AOb + (size_t)blockIdx.y * 128 * Edim, Edim,
                                 Wob + (size_t)blockIdx.x * 128 * Edim, Edim, Edim, acc);
    const int tid = threadIdx.x, lane = tid & 63, w = tid >> 6;
    const int wm = w >> 1, wn = w & 1, lr = lane & 15, lg = lane >> 4;
    #pragma unroll
    for (int mi = 0; mi < 4; ++mi)
        #pragma unroll
        for (int ni = 0; ni < 4; ++ni)
            #pragma unroll
            for (int j = 0; j < 4; ++j) {
                int gm = blockIdx.y * 128 + wm * 64 + mi * 16 + lg * 4 + j;
                int gn = blockIdx.x * 128 + wn * 64 + ni * 16 + lr;
                out[(size_t)gm * Edim + gn] = acc[mi][ni][j] + bo[gn];
            }
}

extern "C" void kernel_launch(void* const* d_in, const int* in_sizes, int n_in,
                              void* d_out, int out_size, void* d_ws, size_t ws_size,
                              hipStream_t stream) {
    const float* query = (const float*)d_in[0];
    const float* key_  = (const float*)d_in[1];
    const float* value = (const float*)d_in[2];
    const float* Wq = (const float*)d_in[3];
    const float* bq = (const float*)d_in[4];
    const float* Wk = (const float*)d_in[5];
    const float* bk = (const float*)d_in[6];
    const float* Wv = (const float*)d_in[7];
    const float* bv = (const float*)d_in[8];
    const float* Wo = (const float*)d_in[9];
    const float* bo = (const float*)d_in[10];

    float* out = (float*)d_out;                      // [4096][1024]
    float* P = out + (size_t)MROWS * Edim;           // [32][2048][2048] attn weights

    const size_t WSZ = (size_t)Edim * Edim;                 // 1M elems per W
    const size_t HSD = (size_t)Bdim * Hdim * Sdim * Ddim;   // 4M elems
    bf16_t* Wb  = (bf16_t*)d_ws;        // 4 x [E,E]  (Wq*0.125, Wk, Wv, Wo)
    bf16_t* Qb  = Wb + 4 * WSZ;         // [B,H,S,D]  (pre-scaled)
    bf16_t* Kb  = Qb + HSD;             // [B,H,S,D]
    bf16_t* Vtb = Kb + HSD;             // [B,H,D,S]
    bf16_t* AOb = Vtb + HSD;            // [B,S,E]

    k_convert<<<dim3(512, 4), 256, 0, stream>>>(Wq, Wk, Wv, Wo, Wb);
    k_proj<<<dim3(8, 32, 3), 256, 0, stream>>>(query, key_, value, Wb,
                                               bq, bk, bv, Qb, Kb, Vtb);
    k_attn<<<dim3(1024), 256, 0, stream>>>(Qb, Kb, Vtb, P, AOb);
    k_oproj<<<dim3(8, 32, 1), 256, 0, stream>>>(AOb, Wb + 3 * WSZ, bo, out);
}

// Round 8
// 528.543 us; speedup vs baseline: 1.0691x; 1.0123x over previous
//
#include <hip/hip_runtime.h>
#include <hip/hip_bf16.h>
#include <cstdint>
#include <cstddef>

#define Bdim 2
#define Sdim 2048
#define Edim 1024
#define Hdim 16
#define Ddim 64
#define KVB 128
#define MROWS (Bdim*Sdim)

typedef __bf16 bf16_t;
typedef __attribute__((ext_vector_type(8))) __bf16 bf16x8;
typedef __attribute__((ext_vector_type(4))) __bf16 bf16x4;
typedef __attribute__((ext_vector_type(4))) float f32x4;

__device__ inline bf16_t f2b(float x) {
    unsigned u = __builtin_bit_cast(unsigned, x);
    unsigned r = u + 0x7fffu + ((u >> 16) & 1u);
    return __builtin_bit_cast(bf16_t, (unsigned short)(r >> 16));
}

// Stage a ROWS x 32 tile (row-major, leading dim ld) into LDS as bf16, rows
// padded to 40 elements. Converts f32 -> bf16 on the fly when T == float.
template<typename T, int ROWS>
__device__ inline void stage_tile(bf16_t* dst, const T* src, int ld, int tid) {
    for (int i = tid; i < ROWS * 4; i += 256) {
        int r = i >> 2;
        int c = (i & 3) * 8;
        const T* s = src + (size_t)r * ld + c;
        bf16x8 v;
        if constexpr (sizeof(T) == 4) {
            const float4* sf = (const float4*)s;
            float4 a = sf[0], b = sf[1];
            v[0] = f2b(a.x); v[1] = f2b(a.y); v[2] = f2b(a.z); v[3] = f2b(a.w);
            v[4] = f2b(b.x); v[5] = f2b(b.y); v[6] = f2b(b.z); v[7] = f2b(b.w);
        } else {
            v = *(const bf16x8*)s;
        }
        *(bf16x8*)(dst + r * 40 + c) = v;
    }
}

// Core: C[128 x BN] += A[128 x K] * B^T, B row-major [BN x K]. 4 waves 2x2.
template<typename TA, typename TB, int FN>
__device__ inline void gemm_core(const TA* A, int lda, const TB* B, int ldb, int K,
                                 f32x4 (&acc)[4][FN]) {
    constexpr int BN = FN * 32;
    __shared__ bf16_t As[128 * 40];
    __shared__ bf16_t Bs[BN * 40];
    const int tid = threadIdx.x;
    const int lane = tid & 63;
    const int w = tid >> 6;
    const int wm = w >> 1, wn = w & 1;
    const int lr = lane & 15, lg = lane >> 4;

    #pragma unroll
    for (int mi = 0; mi < 4; ++mi)
        #pragma unroll
        for (int ni = 0; ni < FN; ++ni)
            acc[mi][ni] = (f32x4){0.f, 0.f, 0.f, 0.f};

    for (int kt = 0; kt < K; kt += 32) {
        __syncthreads();
        stage_tile<TA, 128>(As, A + kt, lda, tid);
        stage_tile<TB, BN>(Bs, B + kt, ldb, tid);
        __syncthreads();
        bf16x8 af[4], bf[FN];
        #pragma unroll
        for (int mi = 0; mi < 4; ++mi)
            af[mi] = *(const bf16x8*)&As[(wm * 64 + mi * 16 + lr) * 40 + lg * 8];
        #pragma unroll
        for (int ni = 0; ni < FN; ++ni)
            bf[ni] = *(const bf16x8*)&Bs[(wn * (FN * 16) + ni * 16 + lr) * 40 + lg * 8];
        #pragma unroll
        for (int mi = 0; mi < 4; ++mi)
            #pragma unroll
            for (int ni = 0; ni < FN; ++ni)
                acc[mi][ni] = __builtin_amdgcn_mfma_f32_16x16x32_bf16(
                    af[mi], bf[ni], acc[mi][ni], 0, 0, 0);
    }
}

// ---- Kernel 0: convert the 4 weight matrices to bf16; Wq scaled by 0.125.
__global__ __launch_bounds__(256) void k_convert(
    const float* __restrict__ Wq, const float* __restrict__ Wk,
    const float* __restrict__ Wv, const float* __restrict__ Wo,
    bf16_t* __restrict__ dst) {
    const int z = blockIdx.y;
    const float* src = (z == 0) ? Wq : (z == 1) ? Wk : (z == 2) ? Wv : Wo;
    const float scale = (z == 0) ? 0.125f : 1.0f;
    bf16_t* d = dst + (size_t)z * Edim * Edim;
    const int i = blockIdx.x * 256 + threadIdx.x;
    const float4* s4 = (const float4*)(src + (size_t)i * 8);
    float4 a = s4[0], b = s4[1];
    bf16x8 v;
    v[0] = f2b(a.x * scale); v[1] = f2b(a.y * scale);
    v[2] = f2b(a.z * scale); v[3] = f2b(a.w * scale);
    v[4] = f2b(b.x * scale); v[5] = f2b(b.y * scale);
    v[6] = f2b(b.z * scale); v[7] = f2b(b.w * scale);
    *(bf16x8*)(d + (size_t)i * 8) = v;
}

// ---- Kernel 1: QKV projections. z = 0/1/2 -> Q/K/V. W pre-converted bf16.
// Q (pre-scaled by 0.125),K -> [B,H,S,D] bf16; V -> transposed [B,H,D,S] bf16.
__global__ __launch_bounds__(256) void k_proj(
    const float* __restrict__ xq, const float* __restrict__ xk, const float* __restrict__ xv,
    const bf16_t* __restrict__ Wb,
    const float* __restrict__ bq, const float* __restrict__ bk, const float* __restrict__ bv,
    bf16_t* __restrict__ Qb, bf16_t* __restrict__ Kb, bf16_t* __restrict__ Vtb) {
    const int z = blockIdx.z;
    const float* X = (z == 0) ? xq : (z == 1) ? xk : xv;
    const bf16_t* W = Wb + (size_t)z * Edim * Edim;
    const float* bias = (z == 0) ? bq : (z == 1) ? bk : bv;
    const float bscale = (z == 0) ? 0.125f : 1.0f;
    const int tm = blockIdx.y, tn = blockIdx.x;
    f32x4 acc[4][4];
    gemm_core<float, bf16_t, 4>(X + (size_t)tm * 128 * Edim, Edim,
                                W + (size_t)tn * 128 * Edim, Edim, Edim, acc);
    const int tid = threadIdx.x, lane = tid & 63, w = tid >> 6;
    const int wm = w >> 1, wn = w & 1, lr = lane & 15, lg = lane >> 4;
    #pragma unroll
    for (int mi = 0; mi < 4; ++mi)
        #pragma unroll
        for (int ni = 0; ni < 4; ++ni)
            #pragma unroll
            for (int j = 0; j < 4; ++j) {
                int gm = tm * 128 + wm * 64 + mi * 16 + lg * 4 + j;
                int gn = tn * 128 + wn * 64 + ni * 16 + lr;
                float v = acc[mi][ni][j] + bias[gn] * bscale;
                int b = gm >> 11, s = gm & (Sdim - 1);
                int h = gn >> 6, d = gn & (Ddim - 1);
                if (z == 2)
                    Vtb[((size_t)(b * Hdim + h) * Ddim + d) * Sdim + s] = f2b(v);
                else if (z == 0)
                    Qb[((size_t)(b * Hdim + h) * Sdim + s) * Ddim + d] = f2b(v);
                else
                    Kb[((size_t)(b * Hdim + h) * Sdim + s) * Ddim + d] = f2b(v);
            }
}

// ---- Kernel 2: fused attention v6 = v5 + store/load reordering.
// vmcnt retires IN ISSUE ORDER: a load issued after a store cannot be waited
// on until the store acks (backpressured by the 537MB P stream). Fix: per
// tile, issue ALL K/V loads FIRST, then the previous tile's P stores (from a
// double-buffered LDS band). Waits on loads then never include older stores.
__global__ __launch_bounds__(256) void k_attn(
    const bf16_t* __restrict__ Qb, const bf16_t* __restrict__ Kb,
    const bf16_t* __restrict__ Vtb, float* __restrict__ P, bf16_t* __restrict__ AOb) {
    // XCD swizzle: block n -> XCD n%8; give XCD k a contiguous bh range.
    const int wg = blockIdx.x;
    const int id = ((wg & 7) << 7) | (wg >> 3);
    const int bh = id >> 5, qt = id & 31;
    const int b = bh >> 4, h = bh & 15;
    const int tid = threadIdx.x, lane = tid & 63, w = tid >> 6;
    const int lr = lane & 15, lg = lane >> 4;

    __shared__ bf16_t Ps[2][4][16][132];   // double-buffered per-wave P bands

    const bf16_t* Qp = Qb + ((size_t)bh * Sdim + qt * 64 + w * 16) * Ddim;
    const bf16_t* Kp = Kb + (size_t)bh * Sdim * Ddim;
    const bf16_t* Vp = Vtb + (size_t)bh * Ddim * Sdim;
    float* Pp = P + (size_t)bh * Sdim * Sdim + (size_t)(qt * 64 + w * 16) * Sdim;

    // Q fragments for this wave's 16 q-rows (pre-scaled by 1/8 at projection).
    bf16x8 qf[2];
    #pragma unroll
    for (int kk = 0; kk < 2; ++kk)
        qf[kk] = *(const bf16x8*)(Qp + lr * Ddim + kk * 32 + lg * 8);

    // ---------------- Phase 1: row sums of exp(s) ----------------
    float lsum[4] = {0.f, 0.f, 0.f, 0.f};
    for (int kt = 0; kt < Sdim / KVB; ++kt) {
        bf16x8 kf[8][2];
        #pragma unroll
        for (int ni = 0; ni < 8; ++ni) {
            const bf16_t* kp = Kp + (size_t)(kt * KVB + ni * 16 + lr) * Ddim;
            kf[ni][0] = *(const bf16x8*)(kp + lg * 8);
            kf[ni][1] = *(const bf16x8*)(kp + 32 + lg * 8);
        }
        f32x4 sacc[8];
        #pragma unroll
        for (int ni = 0; ni < 8; ++ni) {
            sacc[ni] = (f32x4){0.f, 0.f, 0.f, 0.f};
            sacc[ni] = __builtin_amdgcn_mfma_f32_16x16x32_bf16(qf[0], kf[ni][0], sacc[ni], 0, 0, 0);
            sacc[ni] = __builtin_amdgcn_mfma_f32_16x16x32_bf16(qf[1], kf[ni][1], sacc[ni], 0, 0, 0);
        }
        #pragma unroll
        for (int ni = 0; ni < 8; ++ni)
            #pragma unroll
            for (int j = 0; j < 4; ++j)
                lsum[j] += __expf(sacc[ni][j]);
    }
    #pragma unroll
    for (int mask = 1; mask <= 8; mask <<= 1)
        #pragma unroll
        for (int j = 0; j < 4; ++j)
            lsum[j] += __shfl_xor(lsum[j], mask);
    float il[4];
    #pragma unroll
    for (int j = 0; j < 4; ++j) il[j] = 1.0f / lsum[j];

    // ---------------- Phase 2: pipelined P store + O = P.V ----------------
    f32x4 oacc[4];
    #pragma unroll
    for (int nd = 0; nd < 4; ++nd) oacc[nd] = (f32x4){0.f, 0.f, 0.f, 0.f};

    for (int kt = 0; kt < Sdim / KVB; ++kt) {
        const int cur = kt & 1, prev = cur ^ 1;
        // (1) issue ALL loads for this tile first
        bf16x8 kf[8][2];
        #pragma unroll
        for (int ni = 0; ni < 8; ++ni) {
            const bf16_t* kp = Kp + (size_t)(kt * KVB + ni * 16 + lr) * Ddim;
            kf[ni][0] = *(const bf16x8*)(kp + lg * 8);
            kf[ni][1] = *(const bf16x8*)(kp + 32 + lg * 8);
        }
        bf16x8 vf[4][4];
        #pragma unroll
        for (int ks = 0; ks < 4; ++ks)
            #pragma unroll
            for (int nd = 0; nd < 4; ++nd)
                vf[ks][nd] = *(const bf16x8*)(Vp + (size_t)(nd * 16 + lr) * Sdim + kt * KVB + ks * 32 + lg * 8);
        // (2) store previous tile's P band (stores are NEWER than the loads)
        if (kt > 0) {
            #pragma unroll
            for (int i = 0; i < 8; ++i) {
                int row = 2 * i + (lane >> 5);
                int col0 = (lane & 31) * 4;
                bf16x4 p4 = *(const bf16x4*)&Ps[prev][w][row][col0];
                f32x4 o;
                o[0] = (float)p4[0]; o[1] = (float)p4[1];
                o[2] = (float)p4[2]; o[3] = (float)p4[3];
                *(f32x4*)&Pp[(size_t)row * Sdim + (kt - 1) * KVB + col0] = o;
            }
        }
        // (3) scores -> exp -> LDS band cur (waits only on kf)
        #pragma unroll
        for (int ni = 0; ni < 8; ++ni) {
            f32x4 s = (f32x4){0.f, 0.f, 0.f, 0.f};
            s = __builtin_amdgcn_mfma_f32_16x16x32_bf16(qf[0], kf[ni][0], s, 0, 0, 0);
            s = __builtin_amdgcn_mfma_f32_16x16x32_bf16(qf[1], kf[ni][1], s, 0, 0, 0);
            #pragma unroll
            for (int j = 0; j < 4; ++j)
                Ps[cur][w][lg * 4 + j][ni * 16 + lr] = f2b(__expf(s[j]) * il[j]);
        }
        // (4) PV accumulate (waits only on vf + LDS)
        #pragma unroll
        for (int ks = 0; ks < 4; ++ks) {
            bf16x8 pa = *(const bf16x8*)&Ps[cur][w][lr][ks * 32 + lg * 8];
            #pragma unroll
            for (int nd = 0; nd < 4; ++nd)
                oacc[nd] = __builtin_amdgcn_mfma_f32_16x16x32_bf16(pa, vf[ks][nd], oacc[nd], 0, 0, 0);
        }
    }
    // epilogue: store last tile's band (band index 15&1 = 1)
    #pragma unroll
    for (int i = 0; i < 8; ++i) {
        int row = 2 * i + (lane >> 5);
        int col0 = (lane & 31) * 4;
        bf16x4 p4 = *(const bf16x4*)&Ps[1][w][row][col0];
        f32x4 o;
        o[0] = (float)p4[0]; o[1] = (float)p4[1];
        o[2] = (float)p4[2]; o[3] = (float)p4[3];
        *(f32x4*)&Pp[(size_t)row * Sdim + (Sdim - KVB) + col0] = o;
    }

    // epilogue: AO bf16 [B,S,E]
    #pragma unroll
    for (int nd = 0; nd < 4; ++nd)
        #pragma unroll
        for (int j = 0; j < 4; ++j) {
            int s = qt * 64 + w * 16 + lg * 4 + j;
            int d = nd * 16 + lr;
            AOb[((size_t)(b * Sdim + s)) * Edim + h * Ddim + d] = f2b(oacc[nd][j]);
        }
}

// ---- Kernel 3: output = AO @ Wo^T + bo -> d_out f32. Wo pre-converted bf16.
__global__ __launch_bounds__(256) void k_oproj(
    const bf16_t* __restrict__ AOb, const bf16_t* __restrict__ Wob,
    const float* __restrict__ bo, float* __restrict__ out) {
    f32x4 acc[4][4];
    gemm_core<bf16_t, bf16_t, 4>(AOb + (size_t)blockIdx.y * 128 * Edim, Edim,
                                 Wob + (size_t)blockIdx.x * 128 * Edim, Edim, Edim, acc);
    const int tid = threadIdx.x, lane = tid & 63, w = tid >> 6;
    const int wm = w >> 1, wn = w & 1, lr = lane & 15, lg = lane >> 4;
    #pragma unroll
    for (int mi = 0; mi < 4; ++mi)
        #pragma unroll
        for (int ni = 0; ni < 4; ++ni)
            #pragma unroll
            for (int j = 0; j < 4; ++j) {
                int gm = blockIdx.y * 128 + wm * 64 + mi * 16 + lg * 4 + j;
                int gn = blockIdx.x * 128 + wn * 64 + ni * 16 + lr;
                out[(size_t)gm * Edim + gn] = acc[mi][ni][j] + bo[gn];
            }
}

extern "C" void kernel_launch(void* const* d_in, const int* in_sizes, int n_in,
                              void* d_out, int out_size, void* d_ws, size_t ws_size,
                              hipStream_t stream) {
    const float* query = (const float*)d_in[0];
    const float* key_  = (const float*)d_in[1];
    const float* value = (const float*)d_in[2];
    const float* Wq = (const float*)d_in[3];
    const float* bq = (const float*)d_in[4];
    const float* Wk = (const float*)d_in[5];
    const float* bk = (const float*)d_in[6];
    const float* Wv = (const float*)d_in[7];
    const float* bv = (const float*)d_in[8];
    const float* Wo = (const float*)d_in[9];
    const float* bo = (const float*)d_in[10];

    float* out = (float*)d_out;                      // [4096][1024]
    float* P = out + (size_t)MROWS * Edim;           // [32][2048][2048] attn weights

    const size_t WSZ = (size_t)Edim * Edim;                 // 1M elems per W
    const size_t HSD = (size_t)Bdim * Hdim * Sdim * Ddim;   // 4M elems
    bf16_t* Wb  = (bf16_t*)d_ws;        // 4 x [E,E]  (Wq*0.125, Wk, Wv, Wo)
    bf16_t* Qb  = Wb + 4 * WSZ;         // [B,H,S,D]  (pre-scaled)
    bf16_t* Kb  = Qb + HSD;             // [B,H,S,D]
    bf16_t* Vtb = Kb + HSD;             // [B,H,D,S]
    bf16_t* AOb = Vtb + HSD;            // [B,S,E]

    k_convert<<<dim3(512, 4), 256, 0, stream>>>(Wq, Wk, Wv, Wo, Wb);
    k_proj<<<dim3(8, 32, 3), 256, 0, stream>>>(query, key_, value, Wb,
                                               bq, bk, bv, Qb, Kb, Vtb);
    k_attn<<<dim3(1024), 256, 0, stream>>>(Qb, Kb, Vtb, P, AOb);
    k_oproj<<<dim3(8, 32, 1), 256, 0, stream>>>(AOb, Wb + 3 * WSZ, bo, out);
}

// Round 9
// 388.060 us; speedup vs baseline: 1.4561x; 1.3620x over previous
//
#include <hip/hip_runtime.h>
#include <hip/hip_bf16.h>
#include <cstdint>
#include <cstddef>

#define Bdim 2
#define Sdim 2048
#define Edim 1024
#define Hdim 16
#define Ddim 64
#define KVB 128
#define MROWS (Bdim*Sdim)

typedef __bf16 bf16_t;
typedef __attribute__((ext_vector_type(8))) __bf16 bf16x8;
typedef __attribute__((ext_vector_type(4))) __bf16 bf16x4;
typedef __attribute__((ext_vector_type(4))) float f32x4;

__device__ inline bf16_t f2b(float x) {
    unsigned u = __builtin_bit_cast(unsigned, x);
    unsigned r = u + 0x7fffu + ((u >> 16) & 1u);
    return __builtin_bit_cast(bf16_t, (unsigned short)(r >> 16));
}

// Stage a ROWS x 32 tile (row-major, leading dim ld) into LDS as bf16, rows
// padded to 40 elements. Converts f32 -> bf16 on the fly when T == float.
template<typename T, int ROWS>
__device__ inline void stage_tile(bf16_t* dst, const T* src, int ld, int tid) {
    for (int i = tid; i < ROWS * 4; i += 256) {
        int r = i >> 2;
        int c = (i & 3) * 8;
        const T* s = src + (size_t)r * ld + c;
        bf16x8 v;
        if constexpr (sizeof(T) == 4) {
            const float4* sf = (const float4*)s;
            float4 a = sf[0], b = sf[1];
            v[0] = f2b(a.x); v[1] = f2b(a.y); v[2] = f2b(a.z); v[3] = f2b(a.w);
            v[4] = f2b(b.x); v[5] = f2b(b.y); v[6] = f2b(b.z); v[7] = f2b(b.w);
        } else {
            v = *(const bf16x8*)s;
        }
        *(bf16x8*)(dst + r * 40 + c) = v;
    }
}

// Core: C[128 x BN] += A[128 x K] * B^T, B row-major [BN x K]. 4 waves 2x2.
template<typename TA, typename TB, int FN>
__device__ inline void gemm_core(const TA* A, int lda, const TB* B, int ldb, int K,
                                 f32x4 (&acc)[4][FN]) {
    constexpr int BN = FN * 32;
    __shared__ bf16_t As[128 * 40];
    __shared__ bf16_t Bs[BN * 40];
    const int tid = threadIdx.x;
    const int lane = tid & 63;
    const int w = tid >> 6;
    const int wm = w >> 1, wn = w & 1;
    const int lr = lane & 15, lg = lane >> 4;

    #pragma unroll
    for (int mi = 0; mi < 4; ++mi)
        #pragma unroll
        for (int ni = 0; ni < FN; ++ni)
            acc[mi][ni] = (f32x4){0.f, 0.f, 0.f, 0.f};

    for (int kt = 0; kt < K; kt += 32) {
        __syncthreads();
        stage_tile<TA, 128>(As, A + kt, lda, tid);
        stage_tile<TB, BN>(Bs, B + kt, ldb, tid);
        __syncthreads();
        bf16x8 af[4], bf[FN];
        #pragma unroll
        for (int mi = 0; mi < 4; ++mi)
            af[mi] = *(const bf16x8*)&As[(wm * 64 + mi * 16 + lr) * 40 + lg * 8];
        #pragma unroll
        for (int ni = 0; ni < FN; ++ni)
            bf[ni] = *(const bf16x8*)&Bs[(wn * (FN * 16) + ni * 16 + lr) * 40 + lg * 8];
        #pragma unroll
        for (int mi = 0; mi < 4; ++mi)
            #pragma unroll
            for (int ni = 0; ni < FN; ++ni)
                acc[mi][ni] = __builtin_amdgcn_mfma_f32_16x16x32_bf16(
                    af[mi], bf[ni], acc[mi][ni], 0, 0, 0);
    }
}

// ---- Kernel 0: convert the 4 weight matrices to bf16; Wq scaled by 0.125.
__global__ __launch_bounds__(256) void k_convert(
    const float* __restrict__ Wq, const float* __restrict__ Wk,
    const float* __restrict__ Wv, const float* __restrict__ Wo,
    bf16_t* __restrict__ dst) {
    const int z = blockIdx.y;
    const float* src = (z == 0) ? Wq : (z == 1) ? Wk : (z == 2) ? Wv : Wo;
    const float scale = (z == 0) ? 0.125f : 1.0f;
    bf16_t* d = dst + (size_t)z * Edim * Edim;
    const int i = blockIdx.x * 256 + threadIdx.x;
    const float4* s4 = (const float4*)(src + (size_t)i * 8);
    float4 a = s4[0], b = s4[1];
    bf16x8 v;
    v[0] = f2b(a.x * scale); v[1] = f2b(a.y * scale);
    v[2] = f2b(a.z * scale); v[3] = f2b(a.w * scale);
    v[4] = f2b(b.x * scale); v[5] = f2b(b.y * scale);
    v[6] = f2b(b.z * scale); v[7] = f2b(b.w * scale);
    *(bf16x8*)(d + (size_t)i * 8) = v;
}

// ---- Kernel 1: QKV projections. z = 0/1/2 -> Q/K/V. W pre-converted bf16.
// Q (pre-scaled by 0.125) -> [B,H,S,D]; K,V -> MFMA-fragment-major swizzled
// layouts so k_attn's fragment loads are CONTIGUOUS 1KB wave loads:
//   Kswz[bh][s/16][d/8][s%16][d%8]
//   Vswz[bh][s/32][d/16][(s/8)%4][d%16][s%8]
__global__ __launch_bounds__(256) void k_proj(
    const float* __restrict__ xq, const float* __restrict__ xk, const float* __restrict__ xv,
    const bf16_t* __restrict__ Wb,
    const float* __restrict__ bq, const float* __restrict__ bk, const float* __restrict__ bv,
    bf16_t* __restrict__ Qb, bf16_t* __restrict__ Kswz, bf16_t* __restrict__ Vswz) {
    const int z = blockIdx.z;
    const float* X = (z == 0) ? xq : (z == 1) ? xk : xv;
    const bf16_t* W = Wb + (size_t)z * Edim * Edim;
    const float* bias = (z == 0) ? bq : (z == 1) ? bk : bv;
    const float bscale = (z == 0) ? 0.125f : 1.0f;
    const int tm = blockIdx.y, tn = blockIdx.x;
    f32x4 acc[4][4];
    gemm_core<float, bf16_t, 4>(X + (size_t)tm * 128 * Edim, Edim,
                                W + (size_t)tn * 128 * Edim, Edim, Edim, acc);
    const int tid = threadIdx.x, lane = tid & 63, w = tid >> 6;
    const int wm = w >> 1, wn = w & 1, lr = lane & 15, lg = lane >> 4;
    #pragma unroll
    for (int mi = 0; mi < 4; ++mi)
        #pragma unroll
        for (int ni = 0; ni < 4; ++ni)
            #pragma unroll
            for (int j = 0; j < 4; ++j) {
                int gm = tm * 128 + wm * 64 + mi * 16 + lg * 4 + j;
                int gn = tn * 128 + wn * 64 + ni * 16 + lr;
                float v = acc[mi][ni][j] + bias[gn] * bscale;
                int b = gm >> 11, s = gm & (Sdim - 1);
                int h = gn >> 6, d = gn & (Ddim - 1);
                size_t bh = (size_t)(b * Hdim + h);
                if (z == 0) {
                    Qb[(bh * Sdim + s) * Ddim + d] = f2b(v);
                } else if (z == 1) {
                    size_t idx = ((bh * (Sdim / 16) + (s >> 4)) * 8 + (d >> 3)) * 128
                               + (s & 15) * 8 + (d & 7);
                    Kswz[idx] = f2b(v);
                } else {
                    size_t idx = (((bh * (Sdim / 32) + (s >> 5)) * 4 + (d >> 4)) * 4
                               + ((s >> 3) & 3)) * 128 + (d & 15) * 8 + (s & 7);
                    Vswz[idx] = f2b(v);
                }
            }
}

// ---- Kernel 2: fused attention v7 = v6 with fragment-contiguous K/V loads.
// Theory: strided fragment loads touched 16 cache lines per instruction ->
// L1 line-throughput bound (~29K cyc/CU/tile-step, invariant across r3-r8).
// With the swizzled layouts each kf/vf load is one contiguous 1KB wave load.
__global__ __launch_bounds__(256) void k_attn(
    const bf16_t* __restrict__ Qb, const bf16_t* __restrict__ Kswz,
    const bf16_t* __restrict__ Vswz, float* __restrict__ P, bf16_t* __restrict__ AOb) {
    // XCD swizzle: block n -> XCD n%8; give XCD k a contiguous bh range.
    const int wg = blockIdx.x;
    const int id = ((wg & 7) << 7) | (wg >> 3);
    const int bh = id >> 5, qt = id & 31;
    const int b = bh >> 4, h = bh & 15;
    const int tid = threadIdx.x, lane = tid & 63, w = tid >> 6;
    const int lr = lane & 15, lg = lane >> 4;

    __shared__ bf16_t Ps[2][4][16][132];   // double-buffered per-wave P bands

    const bf16_t* Qp = Qb + ((size_t)bh * Sdim + qt * 64 + w * 16) * Ddim;
    const bf16_t* Kp = Kswz + (size_t)bh * Sdim * Ddim;   // fragment-major
    const bf16_t* Vp = Vswz + (size_t)bh * Ddim * Sdim;   // fragment-major
    float* Pp = P + (size_t)bh * Sdim * Sdim + (size_t)(qt * 64 + w * 16) * Sdim;

    // Q fragments for this wave's 16 q-rows (pre-scaled by 1/8 at projection).
    bf16x8 qf[2];
    #pragma unroll
    for (int kk = 0; kk < 2; ++kk)
        qf[kk] = *(const bf16x8*)(Qp + lr * Ddim + kk * 32 + lg * 8);

    // ---------------- Phase 1: row sums of exp(s) ----------------
    float lsum[4] = {0.f, 0.f, 0.f, 0.f};
    for (int kt = 0; kt < Sdim / KVB; ++kt) {
        bf16x8 kf[8][2];
        #pragma unroll
        for (int ni = 0; ni < 8; ++ni) {
            const bf16_t* kp = Kp + (size_t)(kt * 8 + ni) * 1024 + lane * 8;
            kf[ni][0] = *(const bf16x8*)(kp);
            kf[ni][1] = *(const bf16x8*)(kp + 512);
        }
        f32x4 sacc[8];
        #pragma unroll
        for (int ni = 0; ni < 8; ++ni) {
            sacc[ni] = (f32x4){0.f, 0.f, 0.f, 0.f};
            sacc[ni] = __builtin_amdgcn_mfma_f32_16x16x32_bf16(qf[0], kf[ni][0], sacc[ni], 0, 0, 0);
            sacc[ni] = __builtin_amdgcn_mfma_f32_16x16x32_bf16(qf[1], kf[ni][1], sacc[ni], 0, 0, 0);
        }
        #pragma unroll
        for (int ni = 0; ni < 8; ++ni)
            #pragma unroll
            for (int j = 0; j < 4; ++j)
                lsum[j] += __expf(sacc[ni][j]);
    }
    #pragma unroll
    for (int mask = 1; mask <= 8; mask <<= 1)
        #pragma unroll
        for (int j = 0; j < 4; ++j)
            lsum[j] += __shfl_xor(lsum[j], mask);
    float il[4];
    #pragma unroll
    for (int j = 0; j < 4; ++j) il[j] = 1.0f / lsum[j];

    // ---------------- Phase 2: pipelined P store + O = P.V ----------------
    f32x4 oacc[4];
    #pragma unroll
    for (int nd = 0; nd < 4; ++nd) oacc[nd] = (f32x4){0.f, 0.f, 0.f, 0.f};

    for (int kt = 0; kt < Sdim / KVB; ++kt) {
        const int cur = kt & 1, prev = cur ^ 1;
        // (1) issue ALL loads for this tile first (each 1KB contiguous)
        bf16x8 kf[8][2];
        #pragma unroll
        for (int ni = 0; ni < 8; ++ni) {
            const bf16_t* kp = Kp + (size_t)(kt * 8 + ni) * 1024 + lane * 8;
            kf[ni][0] = *(const bf16x8*)(kp);
            kf[ni][1] = *(const bf16x8*)(kp + 512);
        }
        bf16x8 vf[4][4];
        #pragma unroll
        for (int ks = 0; ks < 4; ++ks)
            #pragma unroll
            for (int nd = 0; nd < 4; ++nd)
                vf[ks][nd] = *(const bf16x8*)(Vp + ((size_t)(kt * 4 + ks) * 4 + nd) * 512 + lane * 8);
        // (2) store previous tile's P band
        if (kt > 0) {
            #pragma unroll
            for (int i = 0; i < 8; ++i) {
                int row = 2 * i + (lane >> 5);
                int col0 = (lane & 31) * 4;
                bf16x4 p4 = *(const bf16x4*)&Ps[prev][w][row][col0];
                f32x4 o;
                o[0] = (float)p4[0]; o[1] = (float)p4[1];
                o[2] = (float)p4[2]; o[3] = (float)p4[3];
                *(f32x4*)&Pp[(size_t)row * Sdim + (kt - 1) * KVB + col0] = o;
            }
        }
        // (3) scores -> exp -> LDS band cur
        #pragma unroll
        for (int ni = 0; ni < 8; ++ni) {
            f32x4 s = (f32x4){0.f, 0.f, 0.f, 0.f};
            s = __builtin_amdgcn_mfma_f32_16x16x32_bf16(qf[0], kf[ni][0], s, 0, 0, 0);
            s = __builtin_amdgcn_mfma_f32_16x16x32_bf16(qf[1], kf[ni][1], s, 0, 0, 0);
            #pragma unroll
            for (int j = 0; j < 4; ++j)
                Ps[cur][w][lg * 4 + j][ni * 16 + lr] = f2b(__expf(s[j]) * il[j]);
        }
        // (4) PV accumulate
        #pragma unroll
        for (int ks = 0; ks < 4; ++ks) {
            bf16x8 pa = *(const bf16x8*)&Ps[cur][w][lr][ks * 32 + lg * 8];
            #pragma unroll
            for (int nd = 0; nd < 4; ++nd)
                oacc[nd] = __builtin_amdgcn_mfma_f32_16x16x32_bf16(pa, vf[ks][nd], oacc[nd], 0, 0, 0);
        }
    }
    // epilogue: store last tile's band (band index 15&1 = 1)
    #pragma unroll
    for (int i = 0; i < 8; ++i) {
        int row = 2 * i + (lane >> 5);
        int col0 = (lane & 31) * 4;
        bf16x4 p4 = *(const bf16x4*)&Ps[1][w][row][col0];
        f32x4 o;
        o[0] = (float)p4[0]; o[1] = (float)p4[1];
        o[2] = (float)p4[2]; o[3] = (float)p4[3];
        *(f32x4*)&Pp[(size_t)row * Sdim + (Sdim - KVB) + col0] = o;
    }

    // epilogue: AO bf16 [B,S,E]
    #pragma unroll
    for (int nd = 0; nd < 4; ++nd)
        #pragma unroll
        for (int j = 0; j < 4; ++j) {
            int s = qt * 64 + w * 16 + lg * 4 + j;
            int d = nd * 16 + lr;
            AOb[((size_t)(b * Sdim + s)) * Edim + h * Ddim + d] = f2b(oacc[nd][j]);
        }
}

// ---- Kernel 3: output = AO @ Wo^T + bo -> d_out f32. Wo pre-converted bf16.
__global__ __launch_bounds__(256) void k_oproj(
    const bf16_t* __restrict__ AOb, const bf16_t* __restrict__ Wob,
    const float* __restrict__ bo, float* __restrict__ out) {
    f32x4 acc[4][4];
    gemm_core<bf16_t, bf16_t, 4>(AOb + (size_t)blockIdx.y * 128 * Edim, Edim,
                                 Wob + (size_t)blockIdx.x * 128 * Edim, Edim, Edim, acc);
    const int tid = threadIdx.x, lane = tid & 63, w = tid >> 6;
    const int wm = w >> 1, wn = w & 1, lr = lane & 15, lg = lane >> 4;
    #pragma unroll
    for (int mi = 0; mi < 4; ++mi)
        #pragma unroll
        for (int ni = 0; ni < 4; ++ni)
            #pragma unroll
            for (int j = 0; j < 4; ++j) {
                int gm = blockIdx.y * 128 + wm * 64 + mi * 16 + lg * 4 + j;
                int gn = blockIdx.x * 128 + wn * 64 + ni * 16 + lr;
                out[(size_t)gm * Edim + gn] = acc[mi][ni][j] + bo[gn];
            }
}

extern "C" void kernel_launch(void* const* d_in, const int* in_sizes, int n_in,
                              void* d_out, int out_size, void* d_ws, size_t ws_size,
                              hipStream_t stream) {
    const float* query = (const float*)d_in[0];
    const float* key_  = (const float*)d_in[1];
    const float* value = (const float*)d_in[2];
    const float* Wq = (const float*)d_in[3];
    const float* bq = (const float*)d_in[4];
    const float* Wk = (const float*)d_in[5];
    const float* bk = (const float*)d_in[6];
    const float* Wv = (const float*)d_in[7];
    const float* bv = (const float*)d_in[8];
    const float* Wo = (const float*)d_in[9];
    const float* bo = (const float*)d_in[10];

    float* out = (float*)d_out;                      // [4096][1024]
    float* P = out + (size_t)MROWS * Edim;           // [32][2048][2048] attn weights

    const size_t WSZ = (size_t)Edim * Edim;                 // 1M elems per W
    const size_t HSD = (size_t)Bdim * Hdim * Sdim * Ddim;   // 4M elems
    bf16_t* Wb   = (bf16_t*)d_ws;       // 4 x [E,E]  (Wq*0.125, Wk, Wv, Wo)
    bf16_t* Qb   = Wb + 4 * WSZ;        // [B,H,S,D]  (pre-scaled)
    bf16_t* Kswz = Qb + HSD;            // fragment-major K
    bf16_t* Vswz = Kswz + HSD;          // fragment-major V
    bf16_t* AOb  = Vswz + HSD;          // [B,S,E]

    k_convert<<<dim3(512, 4), 256, 0, stream>>>(Wq, Wk, Wv, Wo, Wb);
    k_proj<<<dim3(8, 32, 3), 256, 0, stream>>>(query, key_, value, Wb,
                                               bq, bk, bv, Qb, Kswz, Vswz);
    k_attn<<<dim3(1024), 256, 0, stream>>>(Qb, Kswz, Vswz, P, AOb);
    k_oproj<<<dim3(8, 32, 1), 256, 0, stream>>>(AOb, Wb + 3 * WSZ, bo, out);
}